// Round 24
// baseline (115.348 us; speedup 1.0000x reference)
//
#include <hip/hip_runtime.h>
#include <hip/hip_bf16.h>

#define B_ 8
#define T_ 2048
#define D_ 128

typedef __attribute__((ext_vector_type(8))) short short8;
typedef __attribute__((ext_vector_type(4))) float f32x4;

static __device__ __forceinline__ short f2bf(float f) {
  __hip_bfloat16 h = __float2bfloat16(f);
  return *reinterpret_cast<short*>(&h);
}

// scale * log2(e):  (1/sqrt(128)) * 1.4426950408889634
#define SL 0.12754434770570355f

// q-supertile = 256 rows (8 waves x 32). ns(qt) = 2qt+2 splits over 8qt+8
// KV-tiles -> exactly 4 tiles per block. UPB = sum ns = 72; 576 blocks.
#define UPB 72

// direct global->LDS, 16B per lane (dest = wave-uniform base + lane*16)
static __device__ __forceinline__ void gl_lds16(const void* g, void* l) {
  __builtin_amdgcn_global_load_lds(
      (const __attribute__((address_space(1))) unsigned*)g,
      (__attribute__((address_space(3))) unsigned*)l, 16, 0, 0);
}

// ---------------------------------------------------------------------------
// Kernel 0: W [128][128] f32 -> W^T [128][128] bf16.
__global__ void wtrans_kernel(const float* __restrict__ Wq, const float* __restrict__ Wk,
                              const float* __restrict__ Wv, __hip_bfloat16* __restrict__ WT) {
  const float* W = (blockIdx.y == 0) ? Wq : (blockIdx.y == 1) ? Wk : Wv;
  int n = blockIdx.x, k = threadIdx.x;
  WT[((size_t)blockIdx.y * 128 + n) * 128 + k] = __float2bfloat16(W[k * 128 + n]);
}

// ---------------------------------------------------------------------------
// Kernel 1: projections, one matrix per blockIdx.y.
// q,k row-major bf16; v stored TRANSPOSED [B][D][T].
__global__ __launch_bounds__(256) void proj_kernel(const float* __restrict__ x,
    const __hip_bfloat16* __restrict__ WT,
    __hip_bfloat16* __restrict__ qp, __hip_bfloat16* __restrict__ kp,
    __hip_bfloat16* __restrict__ vpT) {
  const int wv = threadIdx.x >> 6, lane = threadIdx.x & 63;
  const int ar = lane & 15, kg = lane >> 4;
  const int row0 = blockIdx.x * 64 + wv * 16;
  const int b = row0 >> 11, tloc = row0 & 2047;
  const int m = blockIdx.y;

  short8 a[4];
  {
    const float* px = x + (size_t)(row0 + ar) * 128 + kg * 8;
#pragma unroll
    for (int ks = 0; ks < 4; ++ks) {
      const float* p = px + ks * 32;
      f32x4 x0 = *(const f32x4*)p;
      f32x4 x1 = *(const f32x4*)(p + 4);
      short8 t;
      t[0] = f2bf(x0[0]); t[1] = f2bf(x0[1]); t[2] = f2bf(x0[2]); t[3] = f2bf(x0[3]);
      t[4] = f2bf(x1[0]); t[5] = f2bf(x1[1]); t[6] = f2bf(x1[2]); t[7] = f2bf(x1[3]);
      a[ks] = t;
    }
  }
  const __hip_bfloat16* wt = WT + (size_t)m * 128 * 128;
  if (m < 2) {
    __hip_bfloat16* outp = (m == 0) ? qp : kp;
#pragma unroll
    for (int nt = 0; nt < 8; ++nt) {
      f32x4 acc = {0.f, 0.f, 0.f, 0.f};
#pragma unroll
      for (int ks = 0; ks < 4; ++ks) {
        short8 bfr = *(const short8*)(wt + (nt * 16 + ar) * 128 + ks * 32 + kg * 8);
        acc = __builtin_amdgcn_mfma_f32_16x16x32_bf16(a[ks], bfr, acc, 0, 0, 0);
      }
#pragma unroll
      for (int r = 0; r < 4; ++r)
        outp[(size_t)(row0 + kg * 4 + r) * 128 + nt * 16 + ar] = __float2bfloat16(acc[r]);
    }
  } else {
#pragma unroll
    for (int nt = 0; nt < 8; ++nt) {
      f32x4 acc = {0.f, 0.f, 0.f, 0.f};
#pragma unroll
      for (int ks = 0; ks < 4; ++ks) {
        short8 wfr = *(const short8*)(wt + (nt * 16 + ar) * 128 + ks * 32 + kg * 8);
        acc = __builtin_amdgcn_mfma_f32_16x16x32_bf16(wfr, a[ks], acc, 0, 0, 0);
      }
#pragma unroll
      for (int r = 0; r < 4; ++r)
        vpT[((size_t)b * 128 + nt * 16 + kg * 4 + r) * 2048 + tloc + ar] = __float2bfloat16(acc[r]);
    }
  }
}

// ---------------------------------------------------------------------------
// Kernel 2: causal flash attention (roles swapped: Q'=k_proj, K'=q_proj).
// 8 waves x 32 q-rows = 256-row supertile: halves redundant K/V LDS reads
// AND barrier events per unit work at unchanged 16 waves/CU. Ring-3 KV,
// prefetch issued AFTER the barrier (slot reuse provably safe: barrier(i)
// retires compute(i-1) in all waves). Fixed-m softmax, S^T=mfma(K,Q),
// cvt_pk P-pack. Per-group wave-uniform mask/skip.
__global__ __launch_bounds__(512, 4) void attn_kernel(const __hip_bfloat16* __restrict__ qp,
    const __hip_bfloat16* __restrict__ kp, const __hip_bfloat16* __restrict__ vpT,
    float* __restrict__ out, __hip_bfloat16* __restrict__ po, float* __restrict__ pml,
    int chunked) {
  const int bid = blockIdx.x;
  const int b = bid & 7;            // batch -> XCD pinning
  const int u = bid >> 3;
  int qt, s, ns;
  if (chunked) {
    int g = 0;
#pragma unroll
    for (int i = 1; i < 8; ++i)
      if (u >= i * (i + 1)) g = i;    // base(i) = i*(i+1)
    qt = g; s = u - g * (g + 1); ns = 2 * g + 2;
  } else {
    qt = u; s = 0; ns = 1;
  }
  const int wv = threadIdx.x >> 6, lane = threadIdx.x & 63;
  const int ar = lane & 15, kg = lane >> 4;

  // KV ring: 3 slots x [frag(16)][lane(64) x 16B]; frags 0-7 = K, 8-15 = V
  __shared__ short KV[3][8192];
  __shared__ short Pl[8][32][52];   // [wave][q(32: 2 groups x16)][kv(32)+pad]
  short (*Plw)[52] = Pl[wv];

  const int qrow0 = qt * 256 + wv * 32;   // 32 rows per wave
  const size_t boff = (size_t)b * T_ * 128;
  const size_t bvoff = (size_t)b * 128 * 2048;

  // Q fragments: two 16-row groups
  short8 qf[2][4];
#pragma unroll
  for (int g2 = 0; g2 < 2; ++g2) {
    const __hip_bfloat16* qb = kp + boff + (size_t)(qrow0 + g2 * 16 + ar) * 128 + kg * 8;
#pragma unroll
    for (int ks = 0; ks < 4; ++ks) qf[g2][ks] = *(const short8*)(qb + ks * 32);
  }

  f32x4 o[2][8];
  {
    f32x4 z = {0.f, 0.f, 0.f, 0.f};
#pragma unroll
    for (int g2 = 0; g2 < 2; ++g2)
#pragma unroll
      for (int i = 0; i < 8; ++i) o[g2][i] = z;
  }
  float lpart0 = 0.f, lpart1 = 0.f;

  const int t0 = chunked ? s * 4 : 0;           // ntile/ns == 4 exactly
  const int n = chunked ? 4 : (8 * qt + 8);

  // staging sources for this wave (frag fK = wv, frag fV = 8 + wv)
  const __hip_bfloat16* Ksrc0 = qp + boff + (size_t)((wv >> 2) * 16 + ar) * 128 + (wv & 3) * 32 + kg * 8;
  const __hip_bfloat16* Vsrc0 = vpT + bvoff + (size_t)(wv * 16 + ar) * 2048 + kg * 8;

  // prologue: stage tiles t0, t0+1 into ring slots 0,1
  gl_lds16(Ksrc0 + (size_t)t0 * 4096, &KV[0][wv * 512]);
  gl_lds16(Vsrc0 + (size_t)t0 * 32, &KV[0][(8 + wv) * 512]);
  if (n > 1) {
    gl_lds16(Ksrc0 + (size_t)(t0 + 1) * 4096, &KV[1][wv * 512]);
    gl_lds16(Vsrc0 + (size_t)(t0 + 1) * 32, &KV[1][(8 + wv) * 512]);
  }

  int sl = 0;   // ring slot of tile i
  for (int i = 0; i < n; ++i) {
    const int t = t0 + i;
    // outstanding: tiles {i, i+1 if issued}. Leave i+1's loads in flight.
    if (i + 1 < n) asm volatile("s_waitcnt vmcnt(2)" ::: "memory");
    else           asm volatile("s_waitcnt vmcnt(0)" ::: "memory");
    __builtin_amdgcn_s_barrier();   // all waves: tile i visible, compute(i-1) done
    asm volatile("" ::: "memory");

    // prefetch tile i+2 into tile (i-1)'s slot — safe after the barrier
    int slp = sl + 2; if (slp >= 3) slp -= 3;
    if (i + 2 < n) {
      gl_lds16(Ksrc0 + (size_t)(t + 2) * 4096, &KV[slp][wv * 512]);
      gl_lds16(Vsrc0 + (size_t)(t + 2) * 32, &KV[slp][(8 + wv) * 512]);
    }

    const short* buf = KV[sl];
    sl += 1; if (sl >= 3) sl -= 3;

    const int rel0 = qrow0 - t * 32;            // group 0 (wave-uniform)
    const int rel1 = rel0 + 16;                 // group 1
    const bool act0 = rel0 > -32, act1 = rel1 > -32;  // act0 implies act1
    if (!act1) continue;                        // whole wave-tile masked

#pragma unroll
    for (int g2 = 0; g2 < 2; ++g2) {
      const bool act = (g2 == 0) ? act0 : act1;
      if (!act) continue;
      const int rel = (g2 == 0) ? rel0 : rel1;
      float* lp = (g2 == 0) ? &lpart0 : &lpart1;

      // --- QK: S^T = K Q^T; lane(kg,ar) reg r = S^T[kv=nt*16+kg*4+r][q=ar]
      f32x4 sc[2];
#pragma unroll
      for (int nt = 0; nt < 2; ++nt) {
        f32x4 acc = {0.f, 0.f, 0.f, 0.f};
#pragma unroll
        for (int ks = 0; ks < 4; ++ks) {
          short8 kf = *(const short8*)&buf[(nt * 4 + ks) * 512 + lane * 8];
          acc = __builtin_amdgcn_mfma_f32_16x16x32_bf16(kf, qf[g2][ks], acc, 0, 0, 0);
        }
        sc[nt] = acc;
      }

      // --- P = exp2(s*SL) (fixed m=0); pack 4 bf16 -> one b64 LDS store ---
      if (rel >= 31) {
#pragma unroll
        for (int nt = 0; nt < 2; ++nt) {
          float p0 = exp2f(sc[nt][0] * SL), p1 = exp2f(sc[nt][1] * SL);
          float p2 = exp2f(sc[nt][2] * SL), p3 = exp2f(sc[nt][3] * SL);
          *lp += (p0 + p1) + (p2 + p3);
          unsigned w0, w1;
          asm("v_cvt_pk_bf16_f32 %0, %1, %2" : "=v"(w0) : "v"(p0), "v"(p1));
          asm("v_cvt_pk_bf16_f32 %0, %1, %2" : "=v"(w1) : "v"(p2), "v"(p3));
          *(unsigned long long*)&Plw[g2 * 16 + ar][nt * 16 + kg * 4] =
              ((unsigned long long)w1 << 32) | (unsigned long long)w0;
        }
      } else {
#pragma unroll
        for (int nt = 0; nt < 2; ++nt) {
          float p[4];
#pragma unroll
          for (int r = 0; r < 4; ++r) {
            float v = sc[nt][r];
            if (nt * 16 + kg * 4 + r - rel > ar) v = -3.0e38f;   // kv > q
            p[r] = exp2f(v * SL);
            *lp += p[r];
          }
          unsigned w0, w1;
          asm("v_cvt_pk_bf16_f32 %0, %1, %2" : "=v"(w0) : "v"(p[0]), "v"(p[1]));
          asm("v_cvt_pk_bf16_f32 %0, %1, %2" : "=v"(w1) : "v"(p[2]), "v"(p[3]));
          *(unsigned long long*)&Plw[g2 * 16 + ar][nt * 16 + kg * 4] =
              ((unsigned long long)w1 << 32) | (unsigned long long)w0;
        }
      }
    }

    // --- PV: O += P @ V (V frags read ONCE for both row groups) ---
    short8 pa0 = *(const short8*)&Plw[ar][kg * 8];
    short8 pa1 = *(const short8*)&Plw[16 + ar][kg * 8];
#pragma unroll
    for (int n8 = 0; n8 < 8; ++n8) {
      short8 vf = *(const short8*)&buf[(8 + n8) * 512 + lane * 8];
      if (act0) o[0][n8] = __builtin_amdgcn_mfma_f32_16x16x32_bf16(pa0, vf, o[0][n8], 0, 0, 0);
      o[1][n8] = __builtin_amdgcn_mfma_f32_16x16x32_bf16(pa1, vf, o[1][n8], 0, 0, 0);
    }
  }

  // epilogue: l[q=ar] = sum over the 4 kg-groups; fetch l for q=kg*4+r
  lpart0 += __shfl_xor(lpart0, 16);
  lpart0 += __shfl_xor(lpart0, 32);
  lpart1 += __shfl_xor(lpart1, 16);
  lpart1 += __shfl_xor(lpart1, 32);
  float lq[2][4];
#pragma unroll
  for (int r = 0; r < 4; ++r) {
    lq[0][r] = __shfl(lpart0, kg * 4 + r);
    lq[1][r] = __shfl(lpart1, kg * 4 + r);
  }

  if (ns == 1) {
#pragma unroll
    for (int g2 = 0; g2 < 2; ++g2)
#pragma unroll
      for (int r = 0; r < 4; ++r) lq[g2][r] = 1.f / lq[g2][r];
#pragma unroll
    for (int g2 = 0; g2 < 2; ++g2)
#pragma unroll
      for (int n8 = 0; n8 < 8; ++n8)
#pragma unroll
        for (int r = 0; r < 4; ++r)
          out[boff + (size_t)(qrow0 + g2 * 16 + kg * 4 + r) * 128 + n8 * 16 + ar] =
              o[g2][n8][r] * lq[g2][r];
  } else {
    // partial write (unnormalized bf16 o + f32 l); slot rows = 256
    const int slot = b * UPB + u;
    __hip_bfloat16* pb = po + (size_t)slot * 256 * 128;
#pragma unroll
    for (int g2 = 0; g2 < 2; ++g2)
#pragma unroll
      for (int n8 = 0; n8 < 8; ++n8)
#pragma unroll
        for (int r = 0; r < 4; ++r)
          pb[(wv * 32 + g2 * 16 + kg * 4 + r) * 128 + n8 * 16 + ar] =
              __float2bfloat16(o[g2][n8][r]);
    if (ar == 0) {
#pragma unroll
      for (int g2 = 0; g2 < 2; ++g2)
#pragma unroll
        for (int r = 0; r < 4; ++r)
          pml[slot * 256 + wv * 32 + g2 * 16 + kg * 4 + r] = lq[g2][r];
    }
  }
}

// ---------------------------------------------------------------------------
// Kernel 3: merge splits — ALL rows (every supertile has ns>=2).
// Vectorized: thread = (b, row, 8-float chunk). 8*2048*16/256 = 1024 blocks.
__global__ __launch_bounds__(256) void combine_kernel(const __hip_bfloat16* __restrict__ po,
    const float* __restrict__ pml, float* __restrict__ out) {
  const int g0 = blockIdx.x * 256 + threadIdx.x;
  const int c = g0 & 15;                 // 8-float chunk index
  const int row = (g0 >> 4) & 2047;
  const int b = g0 >> 15;                // [0,8)
  const int qt = row >> 8;
  const int ns = 2 * qt + 2;
  const int rowin = row & 255;
  const int slot0 = b * UPB + qt * (qt + 1);

  f32x4 num0 = {0.f, 0.f, 0.f, 0.f};
  f32x4 num1 = {0.f, 0.f, 0.f, 0.f};
  float den = 0.f;
  for (int s = 0; s < ns; ++s) {
    den += pml[(slot0 + s) * 256 + rowin];
    short8 ov = *(const short8*)(po + (size_t)(slot0 + s) * 256 * 128 + rowin * 128 + c * 8);
#pragma unroll
    for (int i = 0; i < 4; ++i) {
      num0[i] += __uint_as_float(((unsigned)(unsigned short)ov[i]) << 16);
      num1[i] += __uint_as_float(((unsigned)(unsigned short)ov[i + 4]) << 16);
    }
  }
  float inv = 1.f / den;
  f32x4 r0, r1;
#pragma unroll
  for (int i = 0; i < 4; ++i) { r0[i] = num0[i] * inv; r1[i] = num1[i] * inv; }
  float* dst = out + ((size_t)b * 2048 + row) * 128 + c * 8;
  *(f32x4*)dst = r0;
  *(f32x4*)(dst + 4) = r1;
}

// ---------------------------------------------------------------------------
extern "C" void kernel_launch(void* const* d_in, const int* in_sizes, int n_in,
                              void* d_out, int out_size, void* d_ws, size_t ws_size,
                              hipStream_t stream) {
  const float* x  = (const float*)d_in[0];
  const float* Wq = (const float*)d_in[1];
  const float* Wk = (const float*)d_in[2];
  const float* Wv = (const float*)d_in[3];
  float* out = (float*)d_out;

  char* ws = (char*)d_ws;
  __hip_bfloat16* WT  = (__hip_bfloat16*)ws;                        // 96 KB
  __hip_bfloat16* qp  = (__hip_bfloat16*)(ws + 98304);              // 4 MB
  __hip_bfloat16* kp  = qp + (size_t)B_ * T_ * 128;                 // 4 MB
  __hip_bfloat16* vpT = kp + (size_t)B_ * T_ * 128;                 // 4 MB
  __hip_bfloat16* po  = (__hip_bfloat16*)(ws + 98304 + 3 * (size_t)B_ * T_ * 128 * 2); // 37.7 MB
  const size_t nslot = (size_t)8 * UPB;                             // 576
  float* pml = (float*)((char*)po + nslot * 256 * 128 * 2);         // 590 KB

  const size_t need = 98304 + 3 * (size_t)B_ * T_ * 128 * 2
                    + nslot * 256 * 128 * 2 + nslot * 256 * 4;
  const int chunked = (ws_size >= need) ? 1 : 0;

  wtrans_kernel<<<dim3(128, 3), 128, 0, stream>>>(Wq, Wk, Wv, WT);
  proj_kernel<<<dim3(256, 3), 256, 0, stream>>>(x, WT, qp, kp, vpT);
  if (chunked) {
    attn_kernel<<<8 * UPB, 512, 0, stream>>>(qp, kp, vpT, out, po, pml, 1);
    combine_kernel<<<1024, 256, 0, stream>>>(po, pml, out);
  } else {
    attn_kernel<<<64, 512, 0, stream>>>(qp, kp, vpT, out, po, pml, 0);
  }
}

// Round 25
// 60.388 us; speedup vs baseline: 1.9101x; 1.9101x over previous
//
#include <hip/hip_runtime.h>
#include <hip/hip_bf16.h>

#define B_ 8
#define T_ 2048
#define D_ 128

typedef __attribute__((ext_vector_type(8))) short short8;
typedef __attribute__((ext_vector_type(4))) short s16x4;
typedef __attribute__((ext_vector_type(4))) float f32x4;

static __device__ __forceinline__ short f2bf(float f) {
  __hip_bfloat16 h = __float2bfloat16(f);
  return *reinterpret_cast<short*>(&h);
}

// scale * log2(e):  (1/sqrt(128)) * 1.4426950408889634
#define SL 0.12754434770570355f

// q-supertile = 128 rows (8 waves x 16). ns(qt) = ceil((qt+1)/2) splits,
// balanced over 4qt+4 KV-tiles (6-8 tiles per block). UPB = sum ns = 72.
// Per-batch partials = 72 x 32 KB = 2.3 MB < 4 MB XCD L2 (R24 lesson).
#define UPB 72

// cumulative blocks before supertile i (ns: 1,1,2,2,3,3,...):
static __device__ __forceinline__ int base16(int i) {
  int m = i >> 1;
  return (i & 1) ? (m + 1) * (m + 1) : m * m + m;
}

// direct global->LDS, 16B per lane (dest = wave-uniform base + lane*16)
static __device__ __forceinline__ void gl_lds16(const void* g, void* l) {
  __builtin_amdgcn_global_load_lds(
      (const __attribute__((address_space(1))) unsigned*)g,
      (__attribute__((address_space(3))) unsigned*)l, 16, 0, 0);
}

// ---------------------------------------------------------------------------
// Kernel 0: W [128][128] f32 -> W^T [128][128] bf16.
__global__ void wtrans_kernel(const float* __restrict__ Wq, const float* __restrict__ Wk,
                              const float* __restrict__ Wv, __hip_bfloat16* __restrict__ WT) {
  const float* W = (blockIdx.y == 0) ? Wq : (blockIdx.y == 1) ? Wk : Wv;
  int n = blockIdx.x, k = threadIdx.x;
  WT[((size_t)blockIdx.y * 128 + n) * 128 + k] = __float2bfloat16(W[k * 128 + n]);
}

// ---------------------------------------------------------------------------
// Kernel 1: projections, one matrix per blockIdx.y.
// q,k row-major bf16; v stored TRANSPOSED [B][D][T].
__global__ __launch_bounds__(256) void proj_kernel(const float* __restrict__ x,
    const __hip_bfloat16* __restrict__ WT,
    __hip_bfloat16* __restrict__ qp, __hip_bfloat16* __restrict__ kp,
    __hip_bfloat16* __restrict__ vpT) {
  const int wv = threadIdx.x >> 6, lane = threadIdx.x & 63;
  const int ar = lane & 15, kg = lane >> 4;
  const int row0 = blockIdx.x * 64 + wv * 16;
  const int b = row0 >> 11, tloc = row0 & 2047;
  const int m = blockIdx.y;

  short8 a[4];
  {
    const float* px = x + (size_t)(row0 + ar) * 128 + kg * 8;
#pragma unroll
    for (int ks = 0; ks < 4; ++ks) {
      const float* p = px + ks * 32;
      f32x4 x0 = *(const f32x4*)p;
      f32x4 x1 = *(const f32x4*)(p + 4);
      short8 t;
      t[0] = f2bf(x0[0]); t[1] = f2bf(x0[1]); t[2] = f2bf(x0[2]); t[3] = f2bf(x0[3]);
      t[4] = f2bf(x1[0]); t[5] = f2bf(x1[1]); t[6] = f2bf(x1[2]); t[7] = f2bf(x1[3]);
      a[ks] = t;
    }
  }
  const __hip_bfloat16* wt = WT + (size_t)m * 128 * 128;
  if (m < 2) {
    __hip_bfloat16* outp = (m == 0) ? qp : kp;
#pragma unroll
    for (int nt = 0; nt < 8; ++nt) {
      f32x4 acc = {0.f, 0.f, 0.f, 0.f};
#pragma unroll
      for (int ks = 0; ks < 4; ++ks) {
        short8 bfr = *(const short8*)(wt + (nt * 16 + ar) * 128 + ks * 32 + kg * 8);
        acc = __builtin_amdgcn_mfma_f32_16x16x32_bf16(a[ks], bfr, acc, 0, 0, 0);
      }
#pragma unroll
      for (int r = 0; r < 4; ++r)
        outp[(size_t)(row0 + kg * 4 + r) * 128 + nt * 16 + ar] = __float2bfloat16(acc[r]);
    }
  } else {
#pragma unroll
    for (int nt = 0; nt < 8; ++nt) {
      f32x4 acc = {0.f, 0.f, 0.f, 0.f};
#pragma unroll
      for (int ks = 0; ks < 4; ++ks) {
        short8 wfr = *(const short8*)(wt + (nt * 16 + ar) * 128 + ks * 32 + kg * 8);
        acc = __builtin_amdgcn_mfma_f32_16x16x32_bf16(wfr, a[ks], acc, 0, 0, 0);
      }
#pragma unroll
      for (int r = 0; r < 4; ++r)
        vpT[((size_t)b * 128 + nt * 16 + kg * 4 + r) * 2048 + tloc + ar] = __float2bfloat16(acc[r]);
    }
  }
}

// ---------------------------------------------------------------------------
// Kernel 2: causal flash attention (roles swapped: Q'=k_proj, K'=q_proj).
// 8 waves share one 128-row Q-tile; K/V staged once per block into a 4-deep
// LDS ring via global_load_lds; counted-vmcnt barriers. Fixed-m softmax.
// S^T=mfma(K,Q) + cvt_pk P-pack. (Verified best: 60.2 us total.)
__global__ __launch_bounds__(512, 4) void attn_kernel(const __hip_bfloat16* __restrict__ qp,
    const __hip_bfloat16* __restrict__ kp, const __hip_bfloat16* __restrict__ vpT,
    float* __restrict__ out, __hip_bfloat16* __restrict__ po, float* __restrict__ pml,
    int chunked) {
  const int bid = blockIdx.x;
  const int b = bid & 7;            // batch -> XCD pinning
  const int u = bid >> 3;
  int qt, s, ns;
  if (chunked) {
    int g = 0;
#pragma unroll
    for (int i = 1; i < 16; ++i)
      if (u >= base16(i)) g = i;
    qt = g; s = u - base16(g); ns = (g + 2) >> 1;
  } else {
    qt = u; s = 0; ns = 1;
  }
  const int wv = threadIdx.x >> 6, lane = threadIdx.x & 63;
  const int ar = lane & 15, kg = lane >> 4;

  // KV ring: 4 slots x [frag(16)][lane(64) x 16B]; frags 0-7 = K, 8-15 = V
  __shared__ short KV[4][8192];
  __shared__ short Pl[8][16][52];   // [wave][q(16)][kv(32)+pad]
  short (*Plw)[52] = Pl[wv];

  const int qrow0 = qt * 128 + wv * 16;
  const size_t boff = (size_t)b * T_ * 128;
  const size_t bvoff = (size_t)b * 128 * 2048;

  short8 qf[4];
  {
    const __hip_bfloat16* qb = kp + boff + (size_t)(qrow0 + ar) * 128 + kg * 8;
#pragma unroll
    for (int ks = 0; ks < 4; ++ks) qf[ks] = *(const short8*)(qb + ks * 32);
  }

  f32x4 o[8];
  {
    f32x4 z = {0.f, 0.f, 0.f, 0.f};
#pragma unroll
    for (int i = 0; i < 8; ++i) o[i] = z;
  }
  float lpart = 0.f;   // per-lane: sum of P over this lane's kv set, q = ar

  // balanced KV-tile range over ntile = 4qt+4 tiles
  const int ntile = 4 * qt + 4;
  const int t0 = chunked ? (s * ntile) / ns : 0;
  const int t1 = chunked ? ((s + 1) * ntile) / ns : ntile;
  const int n = t1 - t0;

  // staging sources for this wave (frag fK = wv, frag fV = 8 + wv)
  const __hip_bfloat16* Ksrc0 = qp + boff + (size_t)((wv >> 2) * 16 + ar) * 128 + (wv & 3) * 32 + kg * 8;
  const __hip_bfloat16* Vsrc0 = vpT + bvoff + (size_t)(wv * 16 + ar) * 2048 + kg * 8;

  // prologue: stage tiles t0, t0+1 into ring slots 0,1
  gl_lds16(Ksrc0 + (size_t)t0 * 4096, &KV[0][wv * 512]);
  gl_lds16(Vsrc0 + (size_t)t0 * 32, &KV[0][(8 + wv) * 512]);
  if (n > 1) {
    gl_lds16(Ksrc0 + (size_t)(t0 + 1) * 4096, &KV[1][wv * 512]);
    gl_lds16(Vsrc0 + (size_t)(t0 + 1) * 32, &KV[1][(8 + wv) * 512]);
  }

  for (int i = 0; i < n; ++i) {
    const int t = t0 + i;
    if (i + 2 < n) {   // prefetch tile t+2 into ring slot (i+2)&3
      gl_lds16(Ksrc0 + (size_t)(t + 2) * 4096, &KV[(i + 2) & 3][wv * 512]);
      gl_lds16(Vsrc0 + (size_t)(t + 2) * 32, &KV[(i + 2) & 3][(8 + wv) * 512]);
    }
    // counted wait: FIFO completion guarantees tile t's 2 loads landed
    const int rem = n - 1 - i;
    if (rem >= 2)      asm volatile("s_waitcnt vmcnt(4)" ::: "memory");
    else if (rem == 1) asm volatile("s_waitcnt vmcnt(2)" ::: "memory");
    else               asm volatile("s_waitcnt vmcnt(0)" ::: "memory");
    __builtin_amdgcn_s_barrier();
    asm volatile("" ::: "memory");

    const short* buf = KV[i & 3];
    const int rel = qrow0 - t * 32;   // wave-uniform; >=31 -> no mask fires

    // --- QK: S^T = K Q^T; lane(kg,ar) reg r = S^T[kv=nt*16+kg*4+r][q=ar]
    f32x4 sc[2];
#pragma unroll
    for (int nt = 0; nt < 2; ++nt) {
      f32x4 acc = {0.f, 0.f, 0.f, 0.f};
#pragma unroll
      for (int ks = 0; ks < 4; ++ks) {
        short8 kf = *(const short8*)&buf[(nt * 4 + ks) * 512 + lane * 8];
        acc = __builtin_amdgcn_mfma_f32_16x16x32_bf16(kf, qf[ks], acc, 0, 0, 0);
      }
      sc[nt] = acc;
    }

    // --- P = exp2(s*SL) (fixed m=0); pack 4 bf16 -> one b64 LDS store ---
    if (rel >= 31) {
#pragma unroll
      for (int nt = 0; nt < 2; ++nt) {
        float p0 = exp2f(sc[nt][0] * SL), p1 = exp2f(sc[nt][1] * SL);
        float p2 = exp2f(sc[nt][2] * SL), p3 = exp2f(sc[nt][3] * SL);
        lpart += (p0 + p1) + (p2 + p3);
        unsigned w0, w1;
        asm("v_cvt_pk_bf16_f32 %0, %1, %2" : "=v"(w0) : "v"(p0), "v"(p1));
        asm("v_cvt_pk_bf16_f32 %0, %1, %2" : "=v"(w1) : "v"(p2), "v"(p3));
        *(unsigned long long*)&Plw[ar][nt * 16 + kg * 4] =
            ((unsigned long long)w1 << 32) | (unsigned long long)w0;
      }
    } else {
#pragma unroll
      for (int nt = 0; nt < 2; ++nt) {
        float p[4];
#pragma unroll
        for (int r = 0; r < 4; ++r) {
          float v = sc[nt][r];
          if (nt * 16 + kg * 4 + r - rel > ar) v = -3.0e38f;   // kv > q
          p[r] = exp2f(v * SL);
          lpart += p[r];
        }
        unsigned w0, w1;
        asm("v_cvt_pk_bf16_f32 %0, %1, %2" : "=v"(w0) : "v"(p[0]), "v"(p[1]));
        asm("v_cvt_pk_bf16_f32 %0, %1, %2" : "=v"(w1) : "v"(p[2]), "v"(p[3]));
        *(unsigned long long*)&Plw[ar][nt * 16 + kg * 4] =
            ((unsigned long long)w1 << 32) | (unsigned long long)w0;
      }
    }

    // --- PV: O += P @ V (A = P rows from LDS, B = V^T frags) ---
    short8 pa = *(const short8*)&Plw[ar][kg * 8];
#pragma unroll
    for (int n8 = 0; n8 < 8; ++n8) {
      short8 vf = *(const short8*)&buf[(8 + n8) * 512 + lane * 8];
      o[n8] = __builtin_amdgcn_mfma_f32_16x16x32_bf16(pa, vf, o[n8], 0, 0, 0);
    }
  }

  // epilogue: l[q=ar] = sum over the 4 kg-groups; then fetch l for q=kg*4+r
  lpart += __shfl_xor(lpart, 16);
  lpart += __shfl_xor(lpart, 32);
  float lq[4];
#pragma unroll
  for (int r = 0; r < 4; ++r)
    lq[r] = __shfl(lpart, kg * 4 + r);

  if (ns == 1) {
#pragma unroll
    for (int r = 0; r < 4; ++r) lq[r] = 1.f / lq[r];
#pragma unroll
    for (int n8 = 0; n8 < 8; ++n8)
#pragma unroll
      for (int r = 0; r < 4; ++r)
        out[boff + (size_t)(qrow0 + kg * 4 + r) * 128 + n8 * 16 + ar] = o[n8][r] * lq[r];
  } else {
    // partial write (unnormalized bf16 o + f32 l)
    const int slot = b * UPB + u;
    __hip_bfloat16* pb = po + (size_t)slot * 128 * 128;
#pragma unroll
    for (int n8 = 0; n8 < 8; ++n8)
#pragma unroll
      for (int r = 0; r < 4; ++r)
        pb[(wv * 16 + kg * 4 + r) * 128 + n8 * 16 + ar] = __float2bfloat16(o[n8][r]);
    if (ar == 0) {
#pragma unroll
      for (int r = 0; r < 4; ++r)
        pml[slot * 128 + wv * 16 + kg * 4 + r] = lq[r];
    }
  }
}

// ---------------------------------------------------------------------------
// Kernel 3: merge splits for supertiles with ns>=2 (qt>=2: rows 256..2047).
// Vectorized: each thread handles 8 floats (one 16B bf16 load per split).
// thread = (b, row, 8-elem d chunk); grid = 8*1792*16/256 = 896 blocks.
__global__ __launch_bounds__(256) void combine_kernel(const __hip_bfloat16* __restrict__ po,
    const float* __restrict__ pml, float* __restrict__ out) {
  const int g0 = blockIdx.x * 256 + threadIdx.x;
  const int c = g0 & 15;                 // 8-float chunk index
  const int rowm = (g0 >> 4) % 1792;
  const int b = g0 / (1792 * 16);
  const int row = 256 + rowm;
  const int qt = row >> 7;
  const int ns = (qt + 2) >> 1;
  const int rowin = row & 127;
  const int slot0 = b * UPB + base16(qt);

  f32x4 num0 = {0.f, 0.f, 0.f, 0.f};
  f32x4 num1 = {0.f, 0.f, 0.f, 0.f};
  float den = 0.f;
  for (int s = 0; s < ns; ++s) {
    den += pml[(slot0 + s) * 128 + rowin];
    short8 ov = *(const short8*)(po + (size_t)(slot0 + s) * 128 * 128 + rowin * 128 + c * 8);
#pragma unroll
    for (int i = 0; i < 4; ++i) {
      num0[i] += __uint_as_float(((unsigned)(unsigned short)ov[i]) << 16);
      num1[i] += __uint_as_float(((unsigned)(unsigned short)ov[i + 4]) << 16);
    }
  }
  float inv = 1.f / den;
  f32x4 r0, r1;
#pragma unroll
  for (int i = 0; i < 4; ++i) { r0[i] = num0[i] * inv; r1[i] = num1[i] * inv; }
  float* dst = out + ((size_t)b * 2048 + row) * 128 + c * 8;
  *(f32x4*)dst = r0;
  *(f32x4*)(dst + 4) = r1;
}

// ---------------------------------------------------------------------------
extern "C" void kernel_launch(void* const* d_in, const int* in_sizes, int n_in,
                              void* d_out, int out_size, void* d_ws, size_t ws_size,
                              hipStream_t stream) {
  const float* x  = (const float*)d_in[0];
  const float* Wq = (const float*)d_in[1];
  const float* Wk = (const float*)d_in[2];
  const float* Wv = (const float*)d_in[3];
  float* out = (float*)d_out;

  char* ws = (char*)d_ws;
  __hip_bfloat16* WT  = (__hip_bfloat16*)ws;                        // 96 KB
  __hip_bfloat16* qp  = (__hip_bfloat16*)(ws + 98304);              // 4 MB
  __hip_bfloat16* kp  = qp + (size_t)B_ * T_ * 128;                 // 4 MB
  __hip_bfloat16* vpT = kp + (size_t)B_ * T_ * 128;                 // 4 MB
  __hip_bfloat16* po  = (__hip_bfloat16*)(ws + 98304 + 3 * (size_t)B_ * T_ * 128 * 2); // 18.9 MB
  const size_t nslot = (size_t)8 * UPB;                             // 576
  float* pml = (float*)((char*)po + nslot * 128 * 128 * 2);         // 295 KB

  const size_t need = 98304 + 3 * (size_t)B_ * T_ * 128 * 2
                    + nslot * 128 * 128 * 2 + nslot * 128 * 4;
  const int chunked = (ws_size >= need) ? 1 : 0;

  wtrans_kernel<<<dim3(128, 3), 128, 0, stream>>>(Wq, Wk, Wv, WT);
  proj_kernel<<<dim3(256, 3), 256, 0, stream>>>(x, WT, qp, kp, vpT);
  if (chunked) {
    attn_kernel<<<8 * UPB, 512, 0, stream>>>(qp, kp, vpT, out, po, pml, 1);
    combine_kernel<<<896, 256, 0, stream>>>(po, pml, out);
  } else {
    attn_kernel<<<128, 512, 0, stream>>>(qp, kp, vpT, out, po, pml, 0);
  }
}

// Round 26
// 48.024 us; speedup vs baseline: 2.4019x; 1.2574x over previous
//
#include <hip/hip_runtime.h>
#include <hip/hip_bf16.h>

#define B_ 8
#define T_ 2048
#define D_ 128

typedef __attribute__((ext_vector_type(8))) short short8;
typedef __attribute__((ext_vector_type(4))) float f32x4;

static __device__ __forceinline__ short f2bf(float f) {
  __hip_bfloat16 h = __float2bfloat16(f);
  return *reinterpret_cast<short*>(&h);
}

// scale * log2(e):  (1/sqrt(128)) * 1.4426950408889634
#define SL 0.12754434770570355f

// q-supertile = 128 rows (8 waves x 16). ns(qt) = ceil((qt+1)/2) splits,
// balanced over 4qt+4 KV-tiles (6-8 tiles per block). UPB = sum ns = 72.
// Per-batch partials = 72 x 32 KB = 2.3 MB < 4 MB XCD L2 (R24 lesson).
#define UPB 72

// cumulative blocks before supertile i (ns: 1,1,2,2,3,3,...):
static __device__ __forceinline__ int base16(int i) {
  int m = i >> 1;
  return (i & 1) ? (m + 1) * (m + 1) : m * m + m;
}

// direct global->LDS, 16B per lane (dest = wave-uniform base + lane*16)
static __device__ __forceinline__ void gl_lds16(const void* g, void* l) {
  __builtin_amdgcn_global_load_lds(
      (const __attribute__((address_space(1))) unsigned*)g,
      (__attribute__((address_space(3))) unsigned*)l, 16, 0, 0);
}

// ---------------------------------------------------------------------------
// Kernel 1: projections with FUSED W-transpose (wtrans kernel eliminated).
// Each block stages W^T for its matrix m into padded LDS (coalesced global
// reads along n; <=4-way LDS write conflicts), then runs the MFMA GEMM with
// frags read 16B-contiguous from LDS. q,k row-major bf16; v TRANSPOSED.
__global__ __launch_bounds__(256) void proj_kernel(const float* __restrict__ x,
    const float* __restrict__ Wq, const float* __restrict__ Wk,
    const float* __restrict__ Wv,
    __hip_bfloat16* __restrict__ qp, __hip_bfloat16* __restrict__ kp,
    __hip_bfloat16* __restrict__ vpT) {
  const int wv = threadIdx.x >> 6, lane = threadIdx.x & 63;
  const int ar = lane & 15, kg = lane >> 4;
  const int row0 = blockIdx.x * 64 + wv * 16;
  const int b = row0 >> 11, tloc = row0 & 2047;
  const int m = blockIdx.y;

  __shared__ short WTl[128][132];   // W^T[n][k] bf16, +4 pad (4-way banks)

  const float* W = (m == 0) ? Wq : (m == 1) ? Wk : Wv;
  // stage W^T: 16384 elems / 256 thr = 64 per thread, coalesced along n
#pragma unroll
  for (int it = 0; it < 64; ++it) {
    int idx = it * 256 + threadIdx.x;
    int k = idx >> 7, nn = idx & 127;
    WTl[nn][k] = f2bf(W[k * 128 + nn]);
  }

  short8 a[4];
  {
    const float* px = x + (size_t)(row0 + ar) * 128 + kg * 8;
#pragma unroll
    for (int ks = 0; ks < 4; ++ks) {
      const float* p = px + ks * 32;
      f32x4 x0 = *(const f32x4*)p;
      f32x4 x1 = *(const f32x4*)(p + 4);
      short8 t;
      t[0] = f2bf(x0[0]); t[1] = f2bf(x0[1]); t[2] = f2bf(x0[2]); t[3] = f2bf(x0[3]);
      t[4] = f2bf(x1[0]); t[5] = f2bf(x1[1]); t[6] = f2bf(x1[2]); t[7] = f2bf(x1[3]);
      a[ks] = t;
    }
  }
  __syncthreads();   // W^T staged

  if (m < 2) {
    __hip_bfloat16* outp = (m == 0) ? qp : kp;
#pragma unroll
    for (int nt = 0; nt < 8; ++nt) {
      f32x4 acc = {0.f, 0.f, 0.f, 0.f};
#pragma unroll
      for (int ks = 0; ks < 4; ++ks) {
        short8 bfr = *(const short8*)&WTl[nt * 16 + ar][ks * 32 + kg * 8];
        acc = __builtin_amdgcn_mfma_f32_16x16x32_bf16(a[ks], bfr, acc, 0, 0, 0);
      }
#pragma unroll
      for (int r = 0; r < 4; ++r)
        outp[(size_t)(row0 + kg * 4 + r) * 128 + nt * 16 + ar] = __float2bfloat16(acc[r]);
    }
  } else {
#pragma unroll
    for (int nt = 0; nt < 8; ++nt) {
      f32x4 acc = {0.f, 0.f, 0.f, 0.f};
#pragma unroll
      for (int ks = 0; ks < 4; ++ks) {
        short8 wfr = *(const short8*)&WTl[nt * 16 + ar][ks * 32 + kg * 8];
        acc = __builtin_amdgcn_mfma_f32_16x16x32_bf16(wfr, a[ks], acc, 0, 0, 0);
      }
#pragma unroll
      for (int r = 0; r < 4; ++r)
        vpT[((size_t)b * 128 + nt * 16 + kg * 4 + r) * 2048 + tloc + ar] = __float2bfloat16(acc[r]);
    }
  }
}

// ---------------------------------------------------------------------------
// Kernel 2: causal flash attention (roles swapped: Q'=k_proj, K'=q_proj).
// 8 waves share one 128-row Q-tile; K/V staged once per block into a 4-deep
// LDS ring via global_load_lds; counted-vmcnt barriers. Fixed-m softmax.
// S^T=mfma(K,Q) + cvt_pk P-pack. (Verified best: 60.2-60.4 us total.)
__global__ __launch_bounds__(512, 4) void attn_kernel(const __hip_bfloat16* __restrict__ qp,
    const __hip_bfloat16* __restrict__ kp, const __hip_bfloat16* __restrict__ vpT,
    float* __restrict__ out, __hip_bfloat16* __restrict__ po, float* __restrict__ pml,
    int chunked) {
  const int bid = blockIdx.x;
  const int b = bid & 7;            // batch -> XCD pinning
  const int u = bid >> 3;
  int qt, s, ns;
  if (chunked) {
    int g = 0;
#pragma unroll
    for (int i = 1; i < 16; ++i)
      if (u >= base16(i)) g = i;
    qt = g; s = u - base16(g); ns = (g + 2) >> 1;
  } else {
    qt = u; s = 0; ns = 1;
  }
  const int wv = threadIdx.x >> 6, lane = threadIdx.x & 63;
  const int ar = lane & 15, kg = lane >> 4;

  // KV ring: 4 slots x [frag(16)][lane(64) x 16B]; frags 0-7 = K, 8-15 = V
  __shared__ short KV[4][8192];
  __shared__ short Pl[8][16][52];   // [wave][q(16)][kv(32)+pad]
  short (*Plw)[52] = Pl[wv];

  const int qrow0 = qt * 128 + wv * 16;
  const size_t boff = (size_t)b * T_ * 128;
  const size_t bvoff = (size_t)b * 128 * 2048;

  short8 qf[4];
  {
    const __hip_bfloat16* qb = kp + boff + (size_t)(qrow0 + ar) * 128 + kg * 8;
#pragma unroll
    for (int ks = 0; ks < 4; ++ks) qf[ks] = *(const short8*)(qb + ks * 32);
  }

  f32x4 o[8];
  {
    f32x4 z = {0.f, 0.f, 0.f, 0.f};
#pragma unroll
    for (int i = 0; i < 8; ++i) o[i] = z;
  }
  float lpart = 0.f;   // per-lane: sum of P over this lane's kv set, q = ar

  // balanced KV-tile range over ntile = 4qt+4 tiles
  const int ntile = 4 * qt + 4;
  const int t0 = chunked ? (s * ntile) / ns : 0;
  const int t1 = chunked ? ((s + 1) * ntile) / ns : ntile;
  const int n = t1 - t0;

  // staging sources for this wave (frag fK = wv, frag fV = 8 + wv)
  const __hip_bfloat16* Ksrc0 = qp + boff + (size_t)((wv >> 2) * 16 + ar) * 128 + (wv & 3) * 32 + kg * 8;
  const __hip_bfloat16* Vsrc0 = vpT + bvoff + (size_t)(wv * 16 + ar) * 2048 + kg * 8;

  // prologue: stage tiles t0, t0+1 into ring slots 0,1
  gl_lds16(Ksrc0 + (size_t)t0 * 4096, &KV[0][wv * 512]);
  gl_lds16(Vsrc0 + (size_t)t0 * 32, &KV[0][(8 + wv) * 512]);
  if (n > 1) {
    gl_lds16(Ksrc0 + (size_t)(t0 + 1) * 4096, &KV[1][wv * 512]);
    gl_lds16(Vsrc0 + (size_t)(t0 + 1) * 32, &KV[1][(8 + wv) * 512]);
  }

  for (int i = 0; i < n; ++i) {
    const int t = t0 + i;
    if (i + 2 < n) {   // prefetch tile t+2 into ring slot (i+2)&3
      gl_lds16(Ksrc0 + (size_t)(t + 2) * 4096, &KV[(i + 2) & 3][wv * 512]);
      gl_lds16(Vsrc0 + (size_t)(t + 2) * 32, &KV[(i + 2) & 3][(8 + wv) * 512]);
    }
    // counted wait: FIFO completion guarantees tile t's 2 loads landed
    const int rem = n - 1 - i;
    if (rem >= 2)      asm volatile("s_waitcnt vmcnt(4)" ::: "memory");
    else if (rem == 1) asm volatile("s_waitcnt vmcnt(2)" ::: "memory");
    else               asm volatile("s_waitcnt vmcnt(0)" ::: "memory");
    __builtin_amdgcn_s_barrier();
    asm volatile("" ::: "memory");

    const short* buf = KV[i & 3];
    const int rel = qrow0 - t * 32;   // wave-uniform; >=31 -> no mask fires

    // --- QK: S^T = K Q^T; lane(kg,ar) reg r = S^T[kv=nt*16+kg*4+r][q=ar]
    f32x4 sc[2];
#pragma unroll
    for (int nt = 0; nt < 2; ++nt) {
      f32x4 acc = {0.f, 0.f, 0.f, 0.f};
#pragma unroll
      for (int ks = 0; ks < 4; ++ks) {
        short8 kf = *(const short8*)&buf[(nt * 4 + ks) * 512 + lane * 8];
        acc = __builtin_amdgcn_mfma_f32_16x16x32_bf16(kf, qf[ks], acc, 0, 0, 0);
      }
      sc[nt] = acc;
    }

    // --- P = exp2(s*SL) (fixed m=0); pack 4 bf16 -> one b64 LDS store ---
    if (rel >= 31) {
#pragma unroll
      for (int nt = 0; nt < 2; ++nt) {
        float p0 = exp2f(sc[nt][0] * SL), p1 = exp2f(sc[nt][1] * SL);
        float p2 = exp2f(sc[nt][2] * SL), p3 = exp2f(sc[nt][3] * SL);
        lpart += (p0 + p1) + (p2 + p3);
        unsigned w0, w1;
        asm("v_cvt_pk_bf16_f32 %0, %1, %2" : "=v"(w0) : "v"(p0), "v"(p1));
        asm("v_cvt_pk_bf16_f32 %0, %1, %2" : "=v"(w1) : "v"(p2), "v"(p3));
        *(unsigned long long*)&Plw[ar][nt * 16 + kg * 4] =
            ((unsigned long long)w1 << 32) | (unsigned long long)w0;
      }
    } else {
#pragma unroll
      for (int nt = 0; nt < 2; ++nt) {
        float p[4];
#pragma unroll
        for (int r = 0; r < 4; ++r) {
          float v = sc[nt][r];
          if (nt * 16 + kg * 4 + r - rel > ar) v = -3.0e38f;   // kv > q
          p[r] = exp2f(v * SL);
          lpart += p[r];
        }
        unsigned w0, w1;
        asm("v_cvt_pk_bf16_f32 %0, %1, %2" : "=v"(w0) : "v"(p[0]), "v"(p[1]));
        asm("v_cvt_pk_bf16_f32 %0, %1, %2" : "=v"(w1) : "v"(p[2]), "v"(p[3]));
        *(unsigned long long*)&Plw[ar][nt * 16 + kg * 4] =
            ((unsigned long long)w1 << 32) | (unsigned long long)w0;
      }
    }

    // --- PV: O += P @ V (A = P rows from LDS, B = V^T frags) ---
    short8 pa = *(const short8*)&Plw[ar][kg * 8];
#pragma unroll
    for (int n8 = 0; n8 < 8; ++n8) {
      short8 vf = *(const short8*)&buf[(8 + n8) * 512 + lane * 8];
      o[n8] = __builtin_amdgcn_mfma_f32_16x16x32_bf16(pa, vf, o[n8], 0, 0, 0);
    }
  }

  // epilogue: l[q=ar] = sum over the 4 kg-groups; then fetch l for q=kg*4+r
  lpart += __shfl_xor(lpart, 16);
  lpart += __shfl_xor(lpart, 32);
  float lq[4];
#pragma unroll
  for (int r = 0; r < 4; ++r)
    lq[r] = __shfl(lpart, kg * 4 + r);

  if (ns == 1) {
#pragma unroll
    for (int r = 0; r < 4; ++r) lq[r] = 1.f / lq[r];
#pragma unroll
    for (int n8 = 0; n8 < 8; ++n8)
#pragma unroll
      for (int r = 0; r < 4; ++r)
        out[boff + (size_t)(qrow0 + kg * 4 + r) * 128 + n8 * 16 + ar] = o[n8][r] * lq[r];
  } else {
    // partial write (unnormalized bf16 o + f32 l)
    const int slot = b * UPB + u;
    __hip_bfloat16* pb = po + (size_t)slot * 128 * 128;
#pragma unroll
    for (int n8 = 0; n8 < 8; ++n8)
#pragma unroll
      for (int r = 0; r < 4; ++r)
        pb[(wv * 16 + kg * 4 + r) * 128 + n8 * 16 + ar] = __float2bfloat16(o[n8][r]);
    if (ar == 0) {
#pragma unroll
      for (int r = 0; r < 4; ++r)
        pml[slot * 128 + wv * 16 + kg * 4 + r] = lq[r];
    }
  }
}

// ---------------------------------------------------------------------------
// Kernel 3: merge splits for supertiles with ns>=2 (qt>=2: rows 256..2047).
// Vectorized: each thread handles 8 floats (one 16B bf16 load per split).
// thread = (b, row, 8-elem d chunk); grid = 8*1792*16/256 = 896 blocks.
__global__ __launch_bounds__(256) void combine_kernel(const __hip_bfloat16* __restrict__ po,
    const float* __restrict__ pml, float* __restrict__ out) {
  const int g0 = blockIdx.x * 256 + threadIdx.x;
  const int c = g0 & 15;                 // 8-float chunk index
  const int rowm = (g0 >> 4) % 1792;
  const int b = g0 / (1792 * 16);
  const int row = 256 + rowm;
  const int qt = row >> 7;
  const int ns = (qt + 2) >> 1;
  const int rowin = row & 127;
  const int slot0 = b * UPB + base16(qt);

  f32x4 num0 = {0.f, 0.f, 0.f, 0.f};
  f32x4 num1 = {0.f, 0.f, 0.f, 0.f};
  float den = 0.f;
  for (int s = 0; s < ns; ++s) {
    den += pml[(slot0 + s) * 128 + rowin];
    short8 ov = *(const short8*)(po + (size_t)(slot0 + s) * 128 * 128 + rowin * 128 + c * 8);
#pragma unroll
    for (int i = 0; i < 4; ++i) {
      num0[i] += __uint_as_float(((unsigned)(unsigned short)ov[i]) << 16);
      num1[i] += __uint_as_float(((unsigned)(unsigned short)ov[i + 4]) << 16);
    }
  }
  float inv = 1.f / den;
  f32x4 r0, r1;
#pragma unroll
  for (int i = 0; i < 4; ++i) { r0[i] = num0[i] * inv; r1[i] = num1[i] * inv; }
  float* dst = out + ((size_t)b * 2048 + row) * 128 + c * 8;
  *(f32x4*)dst = r0;
  *(f32x4*)(dst + 4) = r1;
}

// ---------------------------------------------------------------------------
extern "C" void kernel_launch(void* const* d_in, const int* in_sizes, int n_in,
                              void* d_out, int out_size, void* d_ws, size_t ws_size,
                              hipStream_t stream) {
  const float* x  = (const float*)d_in[0];
  const float* Wq = (const float*)d_in[1];
  const float* Wk = (const float*)d_in[2];
  const float* Wv = (const float*)d_in[3];
  float* out = (float*)d_out;

  char* ws = (char*)d_ws;
  __hip_bfloat16* qp  = (__hip_bfloat16*)ws;                        // 4 MB
  __hip_bfloat16* kp  = qp + (size_t)B_ * T_ * 128;                 // 4 MB
  __hip_bfloat16* vpT = kp + (size_t)B_ * T_ * 128;                 // 4 MB
  __hip_bfloat16* po  = (__hip_bfloat16*)(ws + 3 * (size_t)B_ * T_ * 128 * 2); // 18.9 MB
  const size_t nslot = (size_t)8 * UPB;                             // 576
  float* pml = (float*)((char*)po + nslot * 128 * 128 * 2);         // 295 KB

  const size_t need = 3 * (size_t)B_ * T_ * 128 * 2
                    + nslot * 128 * 128 * 2 + nslot * 128 * 4;
  const int chunked = (ws_size >= need) ? 1 : 0;

  proj_kernel<<<dim3(256, 3), 256, 0, stream>>>(x, Wq, Wk, Wv, qp, kp, vpT);
  if (chunked) {
    attn_kernel<<<8 * UPB, 512, 0, stream>>>(qp, kp, vpT, out, po, pml, 1);
    combine_kernel<<<896, 256, 0, stream>>>(po, pml, out);
  } else {
    attn_kernel<<<128, 512, 0, stream>>>(qp, kp, vpT, out, po, pml, 0);
  }
}

// Round 27
// 47.565 us; speedup vs baseline: 2.4251x; 1.0097x over previous
//
#include <hip/hip_runtime.h>
#include <hip/hip_bf16.h>

#define B_ 8
#define T_ 2048
#define D_ 128

typedef __attribute__((ext_vector_type(8))) short short8;
typedef __attribute__((ext_vector_type(4))) float f32x4;

static __device__ __forceinline__ short f2bf(float f) {
  __hip_bfloat16 h = __float2bfloat16(f);
  return *reinterpret_cast<short*>(&h);
}

// scale * log2(e):  (1/sqrt(128)) * 1.4426950408889634
#define SL 0.12754434770570355f

// q-supertile = 128 rows (8 waves x 16). ns(qt) = ceil((qt+1)/2) splits,
// balanced over 4qt+4 KV-tiles (6-8 tiles per block). UPB = sum ns = 72.
// Per-batch partials = 72 x 32 KB = 2.3 MB < 4 MB XCD L2 (R24 lesson).
#define UPB 72

// cumulative blocks before supertile i (ns: 1,1,2,2,3,3,...):
static __device__ __forceinline__ int base16(int i) {
  int m = i >> 1;
  return (i & 1) ? (m + 1) * (m + 1) : m * m + m;
}

// direct global->LDS, 16B per lane (dest = wave-uniform base + lane*16)
static __device__ __forceinline__ void gl_lds16(const void* g, void* l) {
  __builtin_amdgcn_global_load_lds(
      (const __attribute__((address_space(1))) unsigned*)g,
      (__attribute__((address_space(3))) unsigned*)l, 16, 0, 0);
}

// ---------------------------------------------------------------------------
// Kernel 1: projections with FUSED W-transpose. Each block stages W^T into
// padded LDS: 32 iters of {2 coalesced f32 loads -> v_cvt_pk -> 1 b32 store}
// (halved staging instructions vs scalar b16). Then the MFMA GEMM reads
// frags 16B-contiguous from LDS. q,k row-major bf16; v TRANSPOSED.
__global__ __launch_bounds__(256) void proj_kernel(const float* __restrict__ x,
    const float* __restrict__ Wq, const float* __restrict__ Wk,
    const float* __restrict__ Wv,
    __hip_bfloat16* __restrict__ qp, __hip_bfloat16* __restrict__ kp,
    __hip_bfloat16* __restrict__ vpT) {
  const int wv = threadIdx.x >> 6, lane = threadIdx.x & 63;
  const int ar = lane & 15, kg = lane >> 4;
  const int row0 = blockIdx.x * 64 + wv * 16;
  const int b = row0 >> 11, tloc = row0 & 2047;
  const int m = blockIdx.y;

  __shared__ short WTl[128][132];   // W^T[n][k] bf16, +4 pad

  const float* W = (m == 0) ? Wq : (m == 1) ? Wk : Wv;
  // stage W^T: 32 iters, each thread covers (nn, k=2kp..2kp+1), coalesced in nn
#pragma unroll
  for (int it = 0; it < 32; ++it) {
    int idx = it * 256 + threadIdx.x;
    int kp2 = idx >> 7, nn = idx & 127;
    float f0 = W[(2 * kp2) * 128 + nn];
    float f1 = W[(2 * kp2 + 1) * 128 + nn];
    unsigned w;
    asm("v_cvt_pk_bf16_f32 %0, %1, %2" : "=v"(w) : "v"(f0), "v"(f1));
    *(unsigned*)&WTl[nn][2 * kp2] = w;
  }

  short8 a[4];
  {
    const float* px = x + (size_t)(row0 + ar) * 128 + kg * 8;
#pragma unroll
    for (int ks = 0; ks < 4; ++ks) {
      const float* p = px + ks * 32;
      f32x4 x0 = *(const f32x4*)p;
      f32x4 x1 = *(const f32x4*)(p + 4);
      short8 t;
      t[0] = f2bf(x0[0]); t[1] = f2bf(x0[1]); t[2] = f2bf(x0[2]); t[3] = f2bf(x0[3]);
      t[4] = f2bf(x1[0]); t[5] = f2bf(x1[1]); t[6] = f2bf(x1[2]); t[7] = f2bf(x1[3]);
      a[ks] = t;
    }
  }
  __syncthreads();   // W^T staged

  if (m < 2) {
    __hip_bfloat16* outp = (m == 0) ? qp : kp;
#pragma unroll
    for (int nt = 0; nt < 8; ++nt) {
      f32x4 acc = {0.f, 0.f, 0.f, 0.f};
#pragma unroll
      for (int ks = 0; ks < 4; ++ks) {
        short8 bfr = *(const short8*)&WTl[nt * 16 + ar][ks * 32 + kg * 8];
        acc = __builtin_amdgcn_mfma_f32_16x16x32_bf16(a[ks], bfr, acc, 0, 0, 0);
      }
#pragma unroll
      for (int r = 0; r < 4; ++r)
        outp[(size_t)(row0 + kg * 4 + r) * 128 + nt * 16 + ar] = __float2bfloat16(acc[r]);
    }
  } else {
#pragma unroll
    for (int nt = 0; nt < 8; ++nt) {
      f32x4 acc = {0.f, 0.f, 0.f, 0.f};
#pragma unroll
      for (int ks = 0; ks < 4; ++ks) {
        short8 wfr = *(const short8*)&WTl[nt * 16 + ar][ks * 32 + kg * 8];
        acc = __builtin_amdgcn_mfma_f32_16x16x32_bf16(wfr, a[ks], acc, 0, 0, 0);
      }
#pragma unroll
      for (int r = 0; r < 4; ++r)
        vpT[((size_t)b * 128 + nt * 16 + kg * 4 + r) * 2048 + tloc + ar] = __float2bfloat16(acc[r]);
    }
  }
}

// ---------------------------------------------------------------------------
// Kernel 2: causal flash attention (roles swapped: Q'=k_proj, K'=q_proj).
// 8 waves share one 128-row Q-tile; K/V staged once per block into a 4-deep
// LDS ring via global_load_lds; counted-vmcnt barriers. Fixed-m softmax.
// S^T=mfma(K,Q) + cvt_pk P-pack. (Verified: 48.0 us total config.)
__global__ __launch_bounds__(512, 4) void attn_kernel(const __hip_bfloat16* __restrict__ qp,
    const __hip_bfloat16* __restrict__ kp, const __hip_bfloat16* __restrict__ vpT,
    float* __restrict__ out, __hip_bfloat16* __restrict__ po, float* __restrict__ pml,
    int chunked) {
  const int bid = blockIdx.x;
  const int b = bid & 7;            // batch -> XCD pinning
  const int u = bid >> 3;
  int qt, s, ns;
  if (chunked) {
    int g = 0;
#pragma unroll
    for (int i = 1; i < 16; ++i)
      if (u >= base16(i)) g = i;
    qt = g; s = u - base16(g); ns = (g + 2) >> 1;
  } else {
    qt = u; s = 0; ns = 1;
  }
  const int wv = threadIdx.x >> 6, lane = threadIdx.x & 63;
  const int ar = lane & 15, kg = lane >> 4;

  // KV ring: 4 slots x [frag(16)][lane(64) x 16B]; frags 0-7 = K, 8-15 = V
  __shared__ short KV[4][8192];
  __shared__ short Pl[8][16][52];   // [wave][q(16)][kv(32)+pad]
  short (*Plw)[52] = Pl[wv];

  const int qrow0 = qt * 128 + wv * 16;
  const size_t boff = (size_t)b * T_ * 128;
  const size_t bvoff = (size_t)b * 128 * 2048;

  short8 qf[4];
  {
    const __hip_bfloat16* qb = kp + boff + (size_t)(qrow0 + ar) * 128 + kg * 8;
#pragma unroll
    for (int ks = 0; ks < 4; ++ks) qf[ks] = *(const short8*)(qb + ks * 32);
  }

  f32x4 o[8];
  {
    f32x4 z = {0.f, 0.f, 0.f, 0.f};
#pragma unroll
    for (int i = 0; i < 8; ++i) o[i] = z;
  }
  float lpart = 0.f;   // per-lane: sum of P over this lane's kv set, q = ar

  // balanced KV-tile range over ntile = 4qt+4 tiles
  const int ntile = 4 * qt + 4;
  const int t0 = chunked ? (s * ntile) / ns : 0;
  const int t1 = chunked ? ((s + 1) * ntile) / ns : ntile;
  const int n = t1 - t0;

  // staging sources for this wave (frag fK = wv, frag fV = 8 + wv)
  const __hip_bfloat16* Ksrc0 = qp + boff + (size_t)((wv >> 2) * 16 + ar) * 128 + (wv & 3) * 32 + kg * 8;
  const __hip_bfloat16* Vsrc0 = vpT + bvoff + (size_t)(wv * 16 + ar) * 2048 + kg * 8;

  // prologue: stage tiles t0, t0+1 into ring slots 0,1
  gl_lds16(Ksrc0 + (size_t)t0 * 4096, &KV[0][wv * 512]);
  gl_lds16(Vsrc0 + (size_t)t0 * 32, &KV[0][(8 + wv) * 512]);
  if (n > 1) {
    gl_lds16(Ksrc0 + (size_t)(t0 + 1) * 4096, &KV[1][wv * 512]);
    gl_lds16(Vsrc0 + (size_t)(t0 + 1) * 32, &KV[1][(8 + wv) * 512]);
  }

  for (int i = 0; i < n; ++i) {
    const int t = t0 + i;
    if (i + 2 < n) {   // prefetch tile t+2 into ring slot (i+2)&3
      gl_lds16(Ksrc0 + (size_t)(t + 2) * 4096, &KV[(i + 2) & 3][wv * 512]);
      gl_lds16(Vsrc0 + (size_t)(t + 2) * 32, &KV[(i + 2) & 3][(8 + wv) * 512]);
    }
    // counted wait: FIFO completion guarantees tile t's 2 loads landed
    const int rem = n - 1 - i;
    if (rem >= 2)      asm volatile("s_waitcnt vmcnt(4)" ::: "memory");
    else if (rem == 1) asm volatile("s_waitcnt vmcnt(2)" ::: "memory");
    else               asm volatile("s_waitcnt vmcnt(0)" ::: "memory");
    __builtin_amdgcn_s_barrier();
    asm volatile("" ::: "memory");

    const short* buf = KV[i & 3];
    const int rel = qrow0 - t * 32;   // wave-uniform; >=31 -> no mask fires

    // --- QK: S^T = K Q^T; lane(kg,ar) reg r = S^T[kv=nt*16+kg*4+r][q=ar]
    f32x4 sc[2];
#pragma unroll
    for (int nt = 0; nt < 2; ++nt) {
      f32x4 acc = {0.f, 0.f, 0.f, 0.f};
#pragma unroll
      for (int ks = 0; ks < 4; ++ks) {
        short8 kf = *(const short8*)&buf[(nt * 4 + ks) * 512 + lane * 8];
        acc = __builtin_amdgcn_mfma_f32_16x16x32_bf16(kf, qf[ks], acc, 0, 0, 0);
      }
      sc[nt] = acc;
    }

    // --- P = exp2(s*SL) (fixed m=0); pack 4 bf16 -> one b64 LDS store ---
    if (rel >= 31) {
#pragma unroll
      for (int nt = 0; nt < 2; ++nt) {
        float p0 = exp2f(sc[nt][0] * SL), p1 = exp2f(sc[nt][1] * SL);
        float p2 = exp2f(sc[nt][2] * SL), p3 = exp2f(sc[nt][3] * SL);
        lpart += (p0 + p1) + (p2 + p3);
        unsigned w0, w1;
        asm("v_cvt_pk_bf16_f32 %0, %1, %2" : "=v"(w0) : "v"(p0), "v"(p1));
        asm("v_cvt_pk_bf16_f32 %0, %1, %2" : "=v"(w1) : "v"(p2), "v"(p3));
        *(unsigned long long*)&Plw[ar][nt * 16 + kg * 4] =
            ((unsigned long long)w1 << 32) | (unsigned long long)w0;
      }
    } else {
#pragma unroll
      for (int nt = 0; nt < 2; ++nt) {
        float p[4];
#pragma unroll
        for (int r = 0; r < 4; ++r) {
          float v = sc[nt][r];
          if (nt * 16 + kg * 4 + r - rel > ar) v = -3.0e38f;   // kv > q
          p[r] = exp2f(v * SL);
          lpart += p[r];
        }
        unsigned w0, w1;
        asm("v_cvt_pk_bf16_f32 %0, %1, %2" : "=v"(w0) : "v"(p[0]), "v"(p[1]));
        asm("v_cvt_pk_bf16_f32 %0, %1, %2" : "=v"(w1) : "v"(p[2]), "v"(p[3]));
        *(unsigned long long*)&Plw[ar][nt * 16 + kg * 4] =
            ((unsigned long long)w1 << 32) | (unsigned long long)w0;
      }
    }

    // --- PV: O += P @ V (A = P rows from LDS, B = V^T frags) ---
    short8 pa = *(const short8*)&Plw[ar][kg * 8];
#pragma unroll
    for (int n8 = 0; n8 < 8; ++n8) {
      short8 vf = *(const short8*)&buf[(8 + n8) * 512 + lane * 8];
      o[n8] = __builtin_amdgcn_mfma_f32_16x16x32_bf16(pa, vf, o[n8], 0, 0, 0);
    }
  }

  // epilogue: l[q=ar] = sum over the 4 kg-groups; then fetch l for q=kg*4+r
  lpart += __shfl_xor(lpart, 16);
  lpart += __shfl_xor(lpart, 32);
  float lq[4];
#pragma unroll
  for (int r = 0; r < 4; ++r)
    lq[r] = __shfl(lpart, kg * 4 + r);

  if (ns == 1) {
#pragma unroll
    for (int r = 0; r < 4; ++r) lq[r] = 1.f / lq[r];
#pragma unroll
    for (int n8 = 0; n8 < 8; ++n8)
#pragma unroll
      for (int r = 0; r < 4; ++r)
        out[boff + (size_t)(qrow0 + kg * 4 + r) * 128 + n8 * 16 + ar] = o[n8][r] * lq[r];
  } else {
    // partial write (unnormalized bf16 o + f32 l)
    const int slot = b * UPB + u;
    __hip_bfloat16* pb = po + (size_t)slot * 128 * 128;
#pragma unroll
    for (int n8 = 0; n8 < 8; ++n8)
#pragma unroll
      for (int r = 0; r < 4; ++r)
        pb[(wv * 16 + kg * 4 + r) * 128 + n8 * 16 + ar] = __float2bfloat16(o[n8][r]);
    if (ar == 0) {
#pragma unroll
      for (int r = 0; r < 4; ++r)
        pml[slot * 128 + wv * 16 + kg * 4 + r] = lq[r];
    }
  }
}

// ---------------------------------------------------------------------------
// Kernel 3: merge splits for supertiles with ns>=2 (qt>=2: rows 256..2047).
// Vectorized: each thread handles 8 floats (one 16B bf16 load per split).
// thread = (b, row, 8-elem d chunk); grid = 8*1792*16/256 = 896 blocks.
__global__ __launch_bounds__(256) void combine_kernel(const __hip_bfloat16* __restrict__ po,
    const float* __restrict__ pml, float* __restrict__ out) {
  const int g0 = blockIdx.x * 256 + threadIdx.x;
  const int c = g0 & 15;                 // 8-float chunk index
  const int rowm = (g0 >> 4) % 1792;
  const int b = g0 / (1792 * 16);
  const int row = 256 + rowm;
  const int qt = row >> 7;
  const int ns = (qt + 2) >> 1;
  const int rowin = row & 127;
  const int slot0 = b * UPB + base16(qt);

  f32x4 num0 = {0.f, 0.f, 0.f, 0.f};
  f32x4 num1 = {0.f, 0.f, 0.f, 0.f};
  float den = 0.f;
  for (int s = 0; s < ns; ++s) {
    den += pml[(slot0 + s) * 128 + rowin];
    short8 ov = *(const short8*)(po + (size_t)(slot0 + s) * 128 * 128 + rowin * 128 + c * 8);
#pragma unroll
    for (int i = 0; i < 4; ++i) {
      num0[i] += __uint_as_float(((unsigned)(unsigned short)ov[i]) << 16);
      num1[i] += __uint_as_float(((unsigned)(unsigned short)ov[i + 4]) << 16);
    }
  }
  float inv = 1.f / den;
  f32x4 r0, r1;
#pragma unroll
  for (int i = 0; i < 4; ++i) { r0[i] = num0[i] * inv; r1[i] = num1[i] * inv; }
  float* dst = out + ((size_t)b * 2048 + row) * 128 + c * 8;
  *(f32x4*)dst = r0;
  *(f32x4*)(dst + 4) = r1;
}

// ---------------------------------------------------------------------------
extern "C" void kernel_launch(void* const* d_in, const int* in_sizes, int n_in,
                              void* d_out, int out_size, void* d_ws, size_t ws_size,
                              hipStream_t stream) {
  const float* x  = (const float*)d_in[0];
  const float* Wq = (const float*)d_in[1];
  const float* Wk = (const float*)d_in[2];
  const float* Wv = (const float*)d_in[3];
  float* out = (float*)d_out;

  char* ws = (char*)d_ws;
  __hip_bfloat16* qp  = (__hip_bfloat16*)ws;                        // 4 MB
  __hip_bfloat16* kp  = qp + (size_t)B_ * T_ * 128;                 // 4 MB
  __hip_bfloat16* vpT = kp + (size_t)B_ * T_ * 128;                 // 4 MB
  __hip_bfloat16* po  = (__hip_bfloat16*)(ws + 3 * (size_t)B_ * T_ * 128 * 2); // 18.9 MB
  const size_t nslot = (size_t)8 * UPB;                             // 576
  float* pml = (float*)((char*)po + nslot * 128 * 128 * 2);         // 295 KB

  const size_t need = 3 * (size_t)B_ * T_ * 128 * 2
                    + nslot * 128 * 128 * 2 + nslot * 128 * 4;
  const int chunked = (ws_size >= need) ? 1 : 0;

  proj_kernel<<<dim3(256, 3), 256, 0, stream>>>(x, Wq, Wk, Wv, qp, kp, vpT);
  if (chunked) {
    attn_kernel<<<8 * UPB, 512, 0, stream>>>(qp, kp, vpT, out, po, pml, 1);
    combine_kernel<<<896, 256, 0, stream>>>(po, pml, out);
  } else {
    attn_kernel<<<128, 512, 0, stream>>>(qp, kp, vpT, out, po, pml, 0);
  }
}

// Round 28
// 47.561 us; speedup vs baseline: 2.4253x; 1.0001x over previous
//
#include <hip/hip_runtime.h>
#include <hip/hip_bf16.h>

#define B_ 8
#define T_ 2048
#define D_ 128

typedef __attribute__((ext_vector_type(8))) short short8;
typedef __attribute__((ext_vector_type(4))) float f32x4;

static __device__ __forceinline__ short f2bf(float f) {
  __hip_bfloat16 h = __float2bfloat16(f);
  return *reinterpret_cast<short*>(&h);
}

// scale * log2(e):  (1/sqrt(128)) * 1.4426950408889634
#define SL 0.12754434770570355f

// q-supertile = 128 rows (8 waves x 16). ns(qt) = ceil((qt+1)/2) splits,
// balanced over 4qt+4 KV-tiles (6-8 tiles per block). UPB = sum ns = 72.
// Per-batch partials = 72 x 32 KB = 2.3 MB < 4 MB XCD L2 (R24 lesson).
#define UPB 72

// cumulative blocks before supertile i (ns: 1,1,2,2,3,3,...):
static __device__ __forceinline__ int base16(int i) {
  int m = i >> 1;
  return (i & 1) ? (m + 1) * (m + 1) : m * m + m;
}

// direct global->LDS, 16B per lane (dest = wave-uniform base + lane*16)
static __device__ __forceinline__ void gl_lds16(const void* g, void* l) {
  __builtin_amdgcn_global_load_lds(
      (const __attribute__((address_space(1))) unsigned*)g,
      (__attribute__((address_space(3))) unsigned*)l, 16, 0, 0);
}

// ---------------------------------------------------------------------------
// Kernel 1: projections with FUSED W-transpose. W^T staged per block into
// padded LDS (coalesced f32 pairs -> cvt_pk -> b32 stores). The kp output
// (attn's Q' operand) is PRE-SCALED by SL so attn's softmax is exp2f(sc)
// with no multiply. q,k row-major bf16; v TRANSPOSED [B][D][T].
__global__ __launch_bounds__(256) void proj_kernel(const float* __restrict__ x,
    const float* __restrict__ Wq, const float* __restrict__ Wk,
    const float* __restrict__ Wv,
    __hip_bfloat16* __restrict__ qp, __hip_bfloat16* __restrict__ kp,
    __hip_bfloat16* __restrict__ vpT) {
  const int wv = threadIdx.x >> 6, lane = threadIdx.x & 63;
  const int ar = lane & 15, kg = lane >> 4;
  const int row0 = blockIdx.x * 64 + wv * 16;
  const int b = row0 >> 11, tloc = row0 & 2047;
  const int m = blockIdx.y;

  __shared__ short WTl[128][132];   // W^T[n][k] bf16, +4 pad

  const float* W = (m == 0) ? Wq : (m == 1) ? Wk : Wv;
  // stage W^T: 32 iters, each thread covers (nn, k=2kp..2kp+1), coalesced in nn
#pragma unroll
  for (int it = 0; it < 32; ++it) {
    int idx = it * 256 + threadIdx.x;
    int kp2 = idx >> 7, nn = idx & 127;
    float f0 = W[(2 * kp2) * 128 + nn];
    float f1 = W[(2 * kp2 + 1) * 128 + nn];
    unsigned w;
    asm("v_cvt_pk_bf16_f32 %0, %1, %2" : "=v"(w) : "v"(f0), "v"(f1));
    *(unsigned*)&WTl[nn][2 * kp2] = w;
  }

  short8 a[4];
  {
    const float* px = x + (size_t)(row0 + ar) * 128 + kg * 8;
#pragma unroll
    for (int ks = 0; ks < 4; ++ks) {
      const float* p = px + ks * 32;
      f32x4 x0 = *(const f32x4*)p;
      f32x4 x1 = *(const f32x4*)(p + 4);
      short8 t;
      t[0] = f2bf(x0[0]); t[1] = f2bf(x0[1]); t[2] = f2bf(x0[2]); t[3] = f2bf(x0[3]);
      t[4] = f2bf(x1[0]); t[5] = f2bf(x1[1]); t[6] = f2bf(x1[2]); t[7] = f2bf(x1[3]);
      a[ks] = t;
    }
  }
  __syncthreads();   // W^T staged

  if (m < 2) {
    __hip_bfloat16* outp = (m == 0) ? qp : kp;
    const float osc = (m == 1) ? SL : 1.0f;   // fold softmax scale into kp
#pragma unroll
    for (int nt = 0; nt < 8; ++nt) {
      f32x4 acc = {0.f, 0.f, 0.f, 0.f};
#pragma unroll
      for (int ks = 0; ks < 4; ++ks) {
        short8 bfr = *(const short8*)&WTl[nt * 16 + ar][ks * 32 + kg * 8];
        acc = __builtin_amdgcn_mfma_f32_16x16x32_bf16(a[ks], bfr, acc, 0, 0, 0);
      }
#pragma unroll
      for (int r = 0; r < 4; ++r)
        outp[(size_t)(row0 + kg * 4 + r) * 128 + nt * 16 + ar] = __float2bfloat16(acc[r] * osc);
    }
  } else {
#pragma unroll
    for (int nt = 0; nt < 8; ++nt) {
      f32x4 acc = {0.f, 0.f, 0.f, 0.f};
#pragma unroll
      for (int ks = 0; ks < 4; ++ks) {
        short8 wfr = *(const short8*)&WTl[nt * 16 + ar][ks * 32 + kg * 8];
        acc = __builtin_amdgcn_mfma_f32_16x16x32_bf16(wfr, a[ks], acc, 0, 0, 0);
      }
#pragma unroll
      for (int r = 0; r < 4; ++r)
        vpT[((size_t)b * 128 + nt * 16 + kg * 4 + r) * 2048 + tloc + ar] = __float2bfloat16(acc[r]);
    }
  }
}

// ---------------------------------------------------------------------------
// Kernel 2: causal flash attention (roles swapped: Q'=k_proj(pre-scaled),
// K'=q_proj). 8 waves share one 128-row Q-tile; K/V staged once per block
// into a 4-deep LDS ring via global_load_lds; counted-vmcnt barriers.
// Fixed-m softmax: P = exp2f(sc) directly (SL folded into kp).
__global__ __launch_bounds__(512, 4) void attn_kernel(const __hip_bfloat16* __restrict__ qp,
    const __hip_bfloat16* __restrict__ kp, const __hip_bfloat16* __restrict__ vpT,
    float* __restrict__ out, __hip_bfloat16* __restrict__ po, float* __restrict__ pml,
    int chunked) {
  const int bid = blockIdx.x;
  const int b = bid & 7;            // batch -> XCD pinning
  const int u = bid >> 3;
  int qt, s, ns;
  if (chunked) {
    int g = 0;
#pragma unroll
    for (int i = 1; i < 16; ++i)
      if (u >= base16(i)) g = i;
    qt = g; s = u - base16(g); ns = (g + 2) >> 1;
  } else {
    qt = u; s = 0; ns = 1;
  }
  const int wv = threadIdx.x >> 6, lane = threadIdx.x & 63;
  const int ar = lane & 15, kg = lane >> 4;

  // KV ring: 4 slots x [frag(16)][lane(64) x 16B]; frags 0-7 = K, 8-15 = V
  __shared__ short KV[4][8192];
  __shared__ short Pl[8][16][52];   // [wave][q(16)][kv(32)+pad]
  short (*Plw)[52] = Pl[wv];

  const int qrow0 = qt * 128 + wv * 16;
  const size_t boff = (size_t)b * T_ * 128;
  const size_t bvoff = (size_t)b * 128 * 2048;

  short8 qf[4];
  {
    const __hip_bfloat16* qb = kp + boff + (size_t)(qrow0 + ar) * 128 + kg * 8;
#pragma unroll
    for (int ks = 0; ks < 4; ++ks) qf[ks] = *(const short8*)(qb + ks * 32);
  }

  f32x4 o[8];
  {
    f32x4 z = {0.f, 0.f, 0.f, 0.f};
#pragma unroll
    for (int i = 0; i < 8; ++i) o[i] = z;
  }
  float lpart = 0.f;   // per-lane: sum of P over this lane's kv set, q = ar

  // balanced KV-tile range over ntile = 4qt+4 tiles
  const int ntile = 4 * qt + 4;
  const int t0 = chunked ? (s * ntile) / ns : 0;
  const int t1 = chunked ? ((s + 1) * ntile) / ns : ntile;
  const int n = t1 - t0;

  // staging sources for this wave (frag fK = wv, frag fV = 8 + wv)
  const __hip_bfloat16* Ksrc0 = qp + boff + (size_t)((wv >> 2) * 16 + ar) * 128 + (wv & 3) * 32 + kg * 8;
  const __hip_bfloat16* Vsrc0 = vpT + bvoff + (size_t)(wv * 16 + ar) * 2048 + kg * 8;

  // prologue: stage tiles t0, t0+1 into ring slots 0,1
  gl_lds16(Ksrc0 + (size_t)t0 * 4096, &KV[0][wv * 512]);
  gl_lds16(Vsrc0 + (size_t)t0 * 32, &KV[0][(8 + wv) * 512]);
  if (n > 1) {
    gl_lds16(Ksrc0 + (size_t)(t0 + 1) * 4096, &KV[1][wv * 512]);
    gl_lds16(Vsrc0 + (size_t)(t0 + 1) * 32, &KV[1][(8 + wv) * 512]);
  }

  for (int i = 0; i < n; ++i) {
    const int t = t0 + i;
    if (i + 2 < n) {   // prefetch tile t+2 into ring slot (i+2)&3
      gl_lds16(Ksrc0 + (size_t)(t + 2) * 4096, &KV[(i + 2) & 3][wv * 512]);
      gl_lds16(Vsrc0 + (size_t)(t + 2) * 32, &KV[(i + 2) & 3][(8 + wv) * 512]);
    }
    // counted wait: FIFO completion guarantees tile t's 2 loads landed
    const int rem = n - 1 - i;
    if (rem >= 2)      asm volatile("s_waitcnt vmcnt(4)" ::: "memory");
    else if (rem == 1) asm volatile("s_waitcnt vmcnt(2)" ::: "memory");
    else               asm volatile("s_waitcnt vmcnt(0)" ::: "memory");
    __builtin_amdgcn_s_barrier();
    asm volatile("" ::: "memory");

    const short* buf = KV[i & 3];
    const int rel = qrow0 - t * 32;   // wave-uniform; >=31 -> no mask fires

    // --- QK: S^T = K Q'^T; lane(kg,ar) reg r = S^T[kv=nt*16+kg*4+r][q=ar]
    f32x4 sc[2];
#pragma unroll
    for (int nt = 0; nt < 2; ++nt) {
      f32x4 acc = {0.f, 0.f, 0.f, 0.f};
#pragma unroll
      for (int ks = 0; ks < 4; ++ks) {
        short8 kf = *(const short8*)&buf[(nt * 4 + ks) * 512 + lane * 8];
        acc = __builtin_amdgcn_mfma_f32_16x16x32_bf16(kf, qf[ks], acc, 0, 0, 0);
      }
      sc[nt] = acc;
    }

    // --- P = exp2f(sc) (SL pre-folded); pack 4 bf16 -> one b64 LDS store ---
    if (rel >= 31) {
#pragma unroll
      for (int nt = 0; nt < 2; ++nt) {
        float p0 = exp2f(sc[nt][0]), p1 = exp2f(sc[nt][1]);
        float p2 = exp2f(sc[nt][2]), p3 = exp2f(sc[nt][3]);
        lpart += (p0 + p1) + (p2 + p3);
        unsigned w0, w1;
        asm("v_cvt_pk_bf16_f32 %0, %1, %2" : "=v"(w0) : "v"(p0), "v"(p1));
        asm("v_cvt_pk_bf16_f32 %0, %1, %2" : "=v"(w1) : "v"(p2), "v"(p3));
        *(unsigned long long*)&Plw[ar][nt * 16 + kg * 4] =
            ((unsigned long long)w1 << 32) | (unsigned long long)w0;
      }
    } else {
#pragma unroll
      for (int nt = 0; nt < 2; ++nt) {
        float p[4];
#pragma unroll
        for (int r = 0; r < 4; ++r) {
          float v = sc[nt][r];
          if (nt * 16 + kg * 4 + r - rel > ar) v = -3.0e38f;   // kv > q
          p[r] = exp2f(v);
          lpart += p[r];
        }
        unsigned w0, w1;
        asm("v_cvt_pk_bf16_f32 %0, %1, %2" : "=v"(w0) : "v"(p[0]), "v"(p[1]));
        asm("v_cvt_pk_bf16_f32 %0, %1, %2" : "=v"(w1) : "v"(p[2]), "v"(p[3]));
        *(unsigned long long*)&Plw[ar][nt * 16 + kg * 4] =
            ((unsigned long long)w1 << 32) | (unsigned long long)w0;
      }
    }

    // --- PV: O += P @ V (A = P rows from LDS, B = V^T frags) ---
    short8 pa = *(const short8*)&Plw[ar][kg * 8];
#pragma unroll
    for (int n8 = 0; n8 < 8; ++n8) {
      short8 vf = *(const short8*)&buf[(8 + n8) * 512 + lane * 8];
      o[n8] = __builtin_amdgcn_mfma_f32_16x16x32_bf16(pa, vf, o[n8], 0, 0, 0);
    }
  }

  // epilogue: l[q=ar] = sum over the 4 kg-groups; then fetch l for q=kg*4+r
  lpart += __shfl_xor(lpart, 16);
  lpart += __shfl_xor(lpart, 32);
  float lq[4];
#pragma unroll
  for (int r = 0; r < 4; ++r)
    lq[r] = __shfl(lpart, kg * 4 + r);

  if (ns == 1) {
#pragma unroll
    for (int r = 0; r < 4; ++r) lq[r] = 1.f / lq[r];
#pragma unroll
    for (int n8 = 0; n8 < 8; ++n8)
#pragma unroll
      for (int r = 0; r < 4; ++r)
        out[boff + (size_t)(qrow0 + kg * 4 + r) * 128 + n8 * 16 + ar] = o[n8][r] * lq[r];
  } else {
    // partial write (unnormalized bf16 o + f32 l)
    const int slot = b * UPB + u;
    __hip_bfloat16* pb = po + (size_t)slot * 128 * 128;
#pragma unroll
    for (int n8 = 0; n8 < 8; ++n8)
#pragma unroll
      for (int r = 0; r < 4; ++r)
        pb[(wv * 16 + kg * 4 + r) * 128 + n8 * 16 + ar] = __float2bfloat16(o[n8][r]);
    if (ar == 0) {
#pragma unroll
      for (int r = 0; r < 4; ++r)
        pml[slot * 128 + wv * 16 + kg * 4 + r] = lq[r];
    }
  }
}

// ---------------------------------------------------------------------------
// Kernel 3: merge splits for supertiles with ns>=2 (qt>=2: rows 256..2047).
// Vectorized: each thread handles 8 floats (one 16B bf16 load per split).
// thread = (b, row, 8-elem d chunk); grid = 8*1792*16/256 = 896 blocks.
__global__ __launch_bounds__(256) void combine_kernel(const __hip_bfloat16* __restrict__ po,
    const float* __restrict__ pml, float* __restrict__ out) {
  const int g0 = blockIdx.x * 256 + threadIdx.x;
  const int c = g0 & 15;                 // 8-float chunk index
  const int rowm = (g0 >> 4) % 1792;
  const int b = g0 / (1792 * 16);
  const int row = 256 + rowm;
  const int qt = row >> 7;
  const int ns = (qt + 2) >> 1;
  const int rowin = row & 127;
  const int slot0 = b * UPB + base16(qt);

  f32x4 num0 = {0.f, 0.f, 0.f, 0.f};
  f32x4 num1 = {0.f, 0.f, 0.f, 0.f};
  float den = 0.f;
  for (int s = 0; s < ns; ++s) {
    den += pml[(slot0 + s) * 128 + rowin];
    short8 ov = *(const short8*)(po + (size_t)(slot0 + s) * 128 * 128 + rowin * 128 + c * 8);
#pragma unroll
    for (int i = 0; i < 4; ++i) {
      num0[i] += __uint_as_float(((unsigned)(unsigned short)ov[i]) << 16);
      num1[i] += __uint_as_float(((unsigned)(unsigned short)ov[i + 4]) << 16);
    }
  }
  float inv = 1.f / den;
  f32x4 r0, r1;
#pragma unroll
  for (int i = 0; i < 4; ++i) { r0[i] = num0[i] * inv; r1[i] = num1[i] * inv; }
  float* dst = out + ((size_t)b * 2048 + row) * 128 + c * 8;
  *(f32x4*)dst = r0;
  *(f32x4*)(dst + 4) = r1;
}

// ---------------------------------------------------------------------------
extern "C" void kernel_launch(void* const* d_in, const int* in_sizes, int n_in,
                              void* d_out, int out_size, void* d_ws, size_t ws_size,
                              hipStream_t stream) {
  const float* x  = (const float*)d_in[0];
  const float* Wq = (const float*)d_in[1];
  const float* Wk = (const float*)d_in[2];
  const float* Wv = (const float*)d_in[3];
  float* out = (float*)d_out;

  char* ws = (char*)d_ws;
  __hip_bfloat16* qp  = (__hip_bfloat16*)ws;                        // 4 MB
  __hip_bfloat16* kp  = qp + (size_t)B_ * T_ * 128;                 // 4 MB
  __hip_bfloat16* vpT = kp + (size_t)B_ * T_ * 128;                 // 4 MB
  __hip_bfloat16* po  = (__hip_bfloat16*)(ws + 3 * (size_t)B_ * T_ * 128 * 2); // 18.9 MB
  const size_t nslot = (size_t)8 * UPB;                             // 576
  float* pml = (float*)((char*)po + nslot * 128 * 128 * 2);         // 295 KB

  const size_t need = 3 * (size_t)B_ * T_ * 128 * 2
                    + nslot * 128 * 128 * 2 + nslot * 128 * 4;
  const int chunked = (ws_size >= need) ? 1 : 0;

  proj_kernel<<<dim3(256, 3), 256, 0, stream>>>(x, Wq, Wk, Wv, qp, kp, vpT);
  if (chunked) {
    attn_kernel<<<8 * UPB, 512, 0, stream>>>(qp, kp, vpT, out, po, pml, 1);
    combine_kernel<<<896, 256, 0, stream>>>(po, pml, out);
  } else {
    attn_kernel<<<128, 512, 0, stream>>>(qp, kp, vpT, out, po, pml, 0);
  }
}